// Round 6
// baseline (231.367 us; speedup 1.0000x reference)
//
#include <hip/hip_runtime.h>

// LocalNetwork, 2 kernels:
//  K1 k_down : 3x4x4 mean downsample -> ds                 (126 MB HBM read)
//  K2 k_rest : per (b,dep): stage 3 ds planes in LDS, depth+lon conv -> u (LDS),
//              lat conv + 12-replica broadcast upsample    (126 MB HBM write)

#define NELEM (15 * 64 * 128)   // 122880 floats per batch item
#define NCELL 2560              // 5*16*32

// ---------------- K1: downsample ----------------
// ds[b][c], c = (id*16+ih)*32+iw
__global__ __launch_bounds__(256) void k_down(const float* __restrict__ x,
                                              float* __restrict__ ds)
{
    const int b  = blockIdx.y;
    const int c  = blockIdx.x * 256 + threadIdx.x;   // [0,2560)
    const int iw = c & 31;
    const int ih = (c >> 5) & 15;
    const int id = c >> 9;

    const float* p = x + (size_t)b * NELEM + ((id * 3) * 64 + ih * 4) * 128 + iw * 4;
    float s = 0.f;
    #pragma unroll
    for (int dd = 0; dd < 3; ++dd) {
        #pragma unroll
        for (int hh = 0; hh < 4; ++hh) {
            const float4 v = *reinterpret_cast<const float4*>(p + (dd * 64 + hh) * 128);
            s += (v.x + v.y) + (v.z + v.w);
        }
    }
    ds[(size_t)b * NCELL + c] = s * (1.f / 48.f);
}

// ---------------- K2: mid convs + lat conv + upsample ----------------
// Block (b,dep), 512 threads. LDS:
//   ds3[kp][ih][iw], kp=0..2 -> id = dep-1+kp (zero-padded outside [0,4];
//     this reproduces both the depth zero-pad k=0/6 AND the flat pads)
//   u_lds[ih][iw]  : lon conv output for this dep
__global__ __launch_bounds__(512) void k_rest(const float* __restrict__ ds,
                                              const float* __restrict__ wd,
                                              const float* __restrict__ bd,
                                              const float* __restrict__ wl,
                                              const float* __restrict__ bl,
                                              const float* __restrict__ wv,
                                              const float* __restrict__ bv,
                                              float* __restrict__ out)
{
    const int b   = blockIdx.y;
    const int dep = blockIdx.x;      // [0,5)
    const int tid = threadIdx.x;     // [0,512)

    __shared__ float ds3[3 * 512];
    __shared__ float u_lds[512];

    // stage 3 ds planes (id = dep-1, dep, dep+1), zero-padded
    for (int i = tid; i < 3 * 512; i += 512) {
        const int kp = i >> 9;
        const int r  = i & 511;
        const int id = dep - 1 + kp;
        ds3[i] = (id >= 0 && id <= 4) ? ds[(size_t)b * NCELL + id * 512 + r] : 0.f;
    }
    __syncthreads();

    // ---- u[dep][ih][iw] = lon conv at m = (dep*16+ih)*34 + iw+1 ----
    {
        const int ih = tid >> 5;
        const int iw = tid & 31;
        const float* dsr = ds3 + ih * 32;   // row base (kp stride = 512)

        // t1local(iwq) = depth conv output at l = (iwq*16+ih)*7 + dep+1
        //   taps: ds3[kp=0..2][ih][iwq]
        auto t1local = [&](int iwq) -> float {
            const int l = (iwq * 16 + ih) * 7 + dep + 1;
            const float y = wd[l * 3 + 0] * dsr[iwq]
                          + wd[l * 3 + 1] * dsr[512 + iwq]
                          + wd[l * 3 + 2] * dsr[1024 + iwq]
                          + bd[l];
            return fmaxf(y, 0.f);
        };
        // lon-padded value at kw' (0..33): 0 outside [1,32]
        auto ulon = [&](int kwq) -> float {
            return (kwq >= 1 && kwq <= 32) ? t1local(kwq - 1) : 0.f;
        };

        const int kw = iw + 1;
        const int m  = (dep * 16 + ih) * 34 + kw;
        const float y = wl[m * 3 + 0] * ulon(kw - 1)
                      + wl[m * 3 + 1] * ulon(kw)
                      + wl[m * 3 + 2] * ulon(kw + 1)
                      + bl[m];
        u_lds[tid] = fmaxf(y, 0.f);
    }
    __syncthreads();

    // ---- v[dep][ihh][iww] + broadcast 12 float4 ----
    {
        const int ihh = tid >> 5;
        const int iww = tid & 31;
        const int n   = (dep * 32 + iww) * 18 + ihh + 1;   // lat flat index

        const float x0 = (ihh > 0)  ? u_lds[(ihh - 1) * 32 + iww] : 0.f;
        const float x1 =              u_lds[ihh * 32 + iww];
        const float x2 = (ihh < 15) ? u_lds[(ihh + 1) * 32 + iww] : 0.f;
        const float y  = fmaxf(wv[n * 3 + 0] * x0 + wv[n * 3 + 1] * x1
                             + wv[n * 3 + 2] * x2 + bv[n], 0.f);
        const float4 y4 = make_float4(y, y, y, y);

        float4* ob = reinterpret_cast<float4*>(out + (size_t)b * NELEM);
        #pragma unroll
        for (int dd = 0; dd < 3; ++dd) {
            #pragma unroll
            for (int hh = 0; hh < 4; ++hh) {
                ob[((dep * 3 + dd) * 64 + ihh * 4 + hh) * 32 + iww] = y4;
            }
        }
    }
}

extern "C" void kernel_launch(void* const* d_in, const int* in_sizes, int n_in,
                              void* d_out, int out_size, void* d_ws, size_t ws_size,
                              hipStream_t stream) {
    const float* x       = (const float*)d_in[0];
    const float* w_depth = (const float*)d_in[1];
    const float* b_depth = (const float*)d_in[2];
    const float* w_lon   = (const float*)d_in[3];
    const float* b_lon   = (const float*)d_in[4];
    const float* w_lat   = (const float*)d_in[5];
    const float* b_lat   = (const float*)d_in[6];
    float* out = (float*)d_out;

    const int Bn = in_sizes[0] / NELEM;   // 256

    float* ds = (float*)d_ws;             // Bn*2560 floats

    k_down<<<dim3(NCELL / 256, Bn), dim3(256), 0, stream>>>(x, ds);
    k_rest<<<dim3(5, Bn), dim3(512), 0, stream>>>(ds, w_depth, b_depth,
                                                  w_lon, b_lon, w_lat, b_lat, out);
}